// Round 1
// baseline (96.550 us; speedup 1.0000x reference)
//
#include <hip/hip_runtime.h>

#define NB 4
#define SS 2048
#define DMODEL 1024
#define DHEAD 64
// SCALE = sqrt(1024) = 32 exactly; folded into Q as *0.03125f

typedef __bf16 bf16x8 __attribute__((ext_vector_type(8)));
typedef float f32x4 __attribute__((ext_vector_type(4)));

#define MFMA16(a, b, c) __builtin_amdgcn_mfma_f32_16x16x32_bf16((a), (b), (c), 0, 0, 0)

// ---------------- Kernel 1: Q/K/V projections ----------------
// grid (64, 3), block 256. blockIdx.y selects weight (0=Q,1=K,2=V).
// Each block: 4 waves x 2 tiles x 16 rows = 128 rows of x @ W (K=1024, N=64).
// W^T staged in LDS as bf16 in K-chunks of 256 (64 x 264 bf16 = 33.8 KB, padded
// so B-frag ds_read_b128 row stride = 528B -> bank +4/row -> 2-way (free)).
#define WT_STRIDE 264

__global__ __launch_bounds__(256) void k1_proj(
    const float* __restrict__ x,
    const float* __restrict__ Wq, const float* __restrict__ bq,
    const float* __restrict__ Wk, const float* __restrict__ bk,
    const float* __restrict__ Wv, const float* __restrict__ bv,
    __bf16* __restrict__ Qo, __bf16* __restrict__ Ko, __bf16* __restrict__ Vt)
{
    __shared__ __bf16 wt[64 * WT_STRIDE];
    const int mode = blockIdx.y;
    const float* W    = (mode == 0) ? Wq : (mode == 1 ? Wk : Wv);
    const float* bias = (mode == 0) ? bq : (mode == 1 ? bk : bv);
    const int tid = threadIdx.x;
    const int lane = tid & 63;
    const int wid = tid >> 6;
    const int l15 = lane & 15;
    const int g = lane >> 4;
    const int wv = blockIdx.x * 4 + wid;   // 0..255

    f32x4 acc[2][4];
    #pragma unroll
    for (int t = 0; t < 2; ++t)
        #pragma unroll
        for (int nt = 0; nt < 4; ++nt)
            acc[t][nt] = (f32x4){0.f, 0.f, 0.f, 0.f};

    for (int kc = 0; kc < 4; ++kc) {
        __syncthreads();   // protect previous chunk's reads
        // stage W^T chunk: W rows [kc*256, kc*256+256) x 64 cols -> wt[n][k_local]
        for (int i = 0; i < 16; ++i) {
            int f4 = tid + 256 * i;       // 0..4095
            int k  = f4 >> 4;             // 0..255
            int nb = (f4 & 15) << 2;      // 0,4,..,60
            f32x4 v = *(const f32x4*)(W + (size_t)(kc * 256 + k) * 64 + nb);
            wt[(nb + 0) * WT_STRIDE + k] = (__bf16)v[0];
            wt[(nb + 1) * WT_STRIDE + k] = (__bf16)v[1];
            wt[(nb + 2) * WT_STRIDE + k] = (__bf16)v[2];
            wt[(nb + 3) * WT_STRIDE + k] = (__bf16)v[3];
        }
        __syncthreads();
        for (int t = 0; t < 2; ++t) {
            int row = (wv * 2 + t) * 16 + l15;           // A-frag row = lane&15
            const float* xrow = x + (size_t)row * DMODEL + kc * 256 + g * 8;
            for (int kk = 0; kk < 8; ++kk) {
                f32x4 a0 = *(const f32x4*)(xrow + kk * 32);
                f32x4 a1 = *(const f32x4*)(xrow + kk * 32 + 4);
                bf16x8 af;
                af[0]=(__bf16)a0[0]; af[1]=(__bf16)a0[1]; af[2]=(__bf16)a0[2]; af[3]=(__bf16)a0[3];
                af[4]=(__bf16)a1[0]; af[5]=(__bf16)a1[1]; af[6]=(__bf16)a1[2]; af[7]=(__bf16)a1[3];
                #pragma unroll
                for (int nt = 0; nt < 4; ++nt) {
                    bf16x8 bfr = *(const bf16x8*)(wt + (nt * 16 + l15) * WT_STRIDE + kk * 32 + g * 8);
                    acc[t][nt] = MFMA16(af, bfr, acc[t][nt]);
                }
            }
        }
    }
    const float scale = (mode == 0) ? 0.03125f : 1.0f;  // fold 1/SCALE into Q
    for (int t = 0; t < 2; ++t) {
        int row0 = (wv * 2 + t) * 16;
        int b  = row0 >> 11;       // 16 | 2048, so tiles never straddle batches
        int s0 = row0 & 2047;
        #pragma unroll
        for (int nt = 0; nt < 4; ++nt) {
            int n = nt * 16 + l15;                      // D col = lane&15
            float bvl = bias[n];
            #pragma unroll
            for (int r = 0; r < 4; ++r) {               // D row = 4*(lane>>4)+r
                float o = (acc[t][nt][r] + bvl) * scale;
                int sr = s0 + g * 4 + r;
                if (mode == 0)      Qo[((size_t)b * SS + sr) * DHEAD + n] = (__bf16)o;
                else if (mode == 1) Ko[((size_t)b * SS + sr) * DHEAD + n] = (__bf16)o;
                else                Vt[((size_t)b * DHEAD + n) * SS + sr] = (__bf16)o;
            }
        }
    }
}

// ---------------- Kernel 2: per-column (per-k) softmax stats ----------------
// grid 512 (4 batch x 128 k-tiles of 16), block 256 (4 waves split q-range).
// S-tile = Q @ K^T: D gives lane col = k (lane&15, fixed per block), rows = q
// -> online (m, sum) per lane, combine over row-groups via shfl, waves via LDS.
__global__ __launch_bounds__(256) void k2_stats(
    const __bf16* __restrict__ Qb, const __bf16* __restrict__ Kb,
    float* __restrict__ mo, float* __restrict__ ro)
{
    __shared__ float lm[4][16], ls[4][16];
    const int tid = threadIdx.x;
    const int wid = tid >> 6;
    const int lane = tid & 63;
    const int l15 = lane & 15;
    const int g = lane >> 4;
    const int b  = blockIdx.x >> 7;
    const int k0 = (blockIdx.x & 127) * 16;

    const __bf16* kp = Kb + ((size_t)b * SS + k0 + l15) * DHEAD + g * 8;
    bf16x8 kb0 = *(const bf16x8*)(kp);
    bf16x8 kb1 = *(const bf16x8*)(kp + 32);
    const __bf16* qp0 = Qb + ((size_t)b * SS + l15) * DHEAD + g * 8;

    float m = -1e30f, ssum = 0.f;
    for (int qt = wid; qt < 128; qt += 4) {
        const __bf16* qp = qp0 + (size_t)qt * 16 * DHEAD;
        bf16x8 a0 = *(const bf16x8*)(qp);
        bf16x8 a1 = *(const bf16x8*)(qp + 32);
        f32x4 sc = (f32x4){0.f, 0.f, 0.f, 0.f};
        sc = MFMA16(a0, kb0, sc);
        sc = MFMA16(a1, kb1, sc);
        float tmax = fmaxf(fmaxf(sc[0], sc[1]), fmaxf(sc[2], sc[3]));
        float mn = fmaxf(m, tmax);
        ssum = ssum * __expf(m - mn)
             + __expf(sc[0] - mn) + __expf(sc[1] - mn)
             + __expf(sc[2] - mn) + __expf(sc[3] - mn);
        m = mn;
    }
    // combine the 4 row-groups (lanes l, l^16, l^32, l^48 share a k-column)
    #pragma unroll
    for (int off = 16; off < 64; off <<= 1) {
        float m2 = __shfl_xor(m, off);
        float s2 = __shfl_xor(ssum, off);
        float mn = fmaxf(m, m2);
        ssum = ssum * __expf(m - mn) + s2 * __expf(m2 - mn);
        m = mn;
    }
    if (g == 0) { lm[wid][l15] = m; ls[wid][l15] = ssum; }
    __syncthreads();
    if (wid == 0 && g == 0) {
        float M = lm[0][l15], Ssum = ls[0][l15];
        #pragma unroll
        for (int w = 1; w < 4; ++w) {
            float m2 = lm[w][l15], s2 = ls[w][l15];
            float mn = fmaxf(M, m2);
            Ssum = Ssum * __expf(M - mn) + s2 * __expf(m2 - mn);
            M = mn;
        }
        mo[b * SS + k0 + l15] = M;
        ro[b * SS + k0 + l15] = 1.0f / Ssum;
    }
}

// ---------------- Kernel 3: out = (softmax(S)+mask) @ V ----------------
// grid 512 (4 batch x 128 q-tiles of 16), block 256; 4 waves split the k-range
// (each wave: 16 k-chunks of 32), LDS-reduce partial accumulators at the end.
// Per chunk: S-tile MFMA -> p=exp(s-m)*rl -> LDS (D-layout -> A-layout
// transpose, stride 36 floats = 16B-aligned, 2-way banks = free) -> +mask in
// f32 -> bf16 A-frag -> 4 PV MFMAs against V^T B-frags.
__global__ __launch_bounds__(256) void k3_out(
    const __bf16* __restrict__ Qb, const __bf16* __restrict__ Kb,
    const __bf16* __restrict__ Vt, const float* __restrict__ mask,
    const float* __restrict__ marr, const float* __restrict__ rarr,
    float* __restrict__ out)
{
    __shared__ float plds[4][16 * 36];
    __shared__ f32x4 red[4][4][64];
    const int tid = threadIdx.x;
    const int wid = tid >> 6;
    const int lane = tid & 63;
    const int l15 = lane & 15;
    const int g = lane >> 4;
    const int b  = blockIdx.x >> 7;
    const int q0 = (blockIdx.x & 127) * 16;

    const __bf16* qp = Qb + ((size_t)b * SS + q0 + l15) * DHEAD + g * 8;
    bf16x8 qa0 = *(const bf16x8*)(qp);
    bf16x8 qa1 = *(const bf16x8*)(qp + 32);
    f32x4 acc[4];
    #pragma unroll
    for (int nt = 0; nt < 4; ++nt) acc[nt] = (f32x4){0.f, 0.f, 0.f, 0.f};
    float* myp = plds[wid];
    const float* mrow = mask + ((size_t)b * SS + q0 + l15) * SS;

    for (int kc = wid; kc < 64; kc += 4) {
        #pragma unroll
        for (int t = 0; t < 2; ++t) {
            int k0 = kc * 32 + t * 16;
            const __bf16* kp = Kb + ((size_t)b * SS + k0 + l15) * DHEAD + g * 8;
            bf16x8 kb0 = *(const bf16x8*)(kp);
            bf16x8 kb1 = *(const bf16x8*)(kp + 32);
            f32x4 sc = (f32x4){0.f, 0.f, 0.f, 0.f};
            sc = MFMA16(qa0, kb0, sc);
            sc = MFMA16(qa1, kb1, sc);
            float mv = marr[b * SS + k0 + l15];
            float rv = rarr[b * SS + k0 + l15];
            #pragma unroll
            for (int r = 0; r < 4; ++r)   // D: row q=4g+r, col k=l15
                myp[(g * 4 + r) * 36 + t * 16 + l15] = __expf(sc[r] - mv) * rv;
        }
        int koff = kc * 32 + g * 8;
        f32x4 mk0 = *(const f32x4*)(mrow + koff);
        f32x4 mk1 = *(const f32x4*)(mrow + koff + 4);
        const float* pr = myp + l15 * 36 + g * 8;   // A-frag: row q=l15, k=8g+i
        f32x4 p0 = *(const f32x4*)(pr);
        f32x4 p1 = *(const f32x4*)(pr + 4);
        bf16x8 af;
        af[0]=(__bf16)(p0[0]+mk0[0]); af[1]=(__bf16)(p0[1]+mk0[1]);
        af[2]=(__bf16)(p0[2]+mk0[2]); af[3]=(__bf16)(p0[3]+mk0[3]);
        af[4]=(__bf16)(p1[0]+mk1[0]); af[5]=(__bf16)(p1[1]+mk1[1]);
        af[6]=(__bf16)(p1[2]+mk1[2]); af[7]=(__bf16)(p1[3]+mk1[3]);
        #pragma unroll
        for (int nt = 0; nt < 4; ++nt) {
            bf16x8 vb = *(const bf16x8*)(Vt + ((size_t)b * DHEAD + nt * 16 + l15) * SS + koff);
            acc[nt] = MFMA16(af, vb, acc[nt]);
        }
    }
    #pragma unroll
    for (int nt = 0; nt < 4; ++nt) red[wid][nt][lane] = acc[nt];
    __syncthreads();
    if (wid == 0) {
        #pragma unroll
        for (int nt = 0; nt < 4; ++nt) {
            f32x4 a = red[0][nt][lane] + red[1][nt][lane]
                    + red[2][nt][lane] + red[3][nt][lane];
            #pragma unroll
            for (int r = 0; r < 4; ++r)
                out[((size_t)b * SS + q0 + g * 4 + r) * DHEAD + nt * 16 + l15] = a[r];
        }
    }
}

extern "C" void kernel_launch(void* const* d_in, const int* in_sizes, int n_in,
                              void* d_out, int out_size, void* d_ws, size_t ws_size,
                              hipStream_t stream)
{
    const float* x    = (const float*)d_in[0];
    const float* mask = (const float*)d_in[1];
    const float* Wq   = (const float*)d_in[2];
    const float* bq   = (const float*)d_in[3];
    const float* Wk   = (const float*)d_in[4];
    const float* bk   = (const float*)d_in[5];
    const float* Wv   = (const float*)d_in[6];
    const float* bv   = (const float*)d_in[7];
    float* out = (float*)d_out;

    // ws layout (3.11 MB): Qbf 1MB | Kbf 1MB | Vt 1MB | m 32KB | rl 32KB
    char* ws = (char*)d_ws;
    __bf16* Qbf = (__bf16*)(ws);
    __bf16* Kbf = (__bf16*)(ws + (1u << 20));
    __bf16* Vt  = (__bf16*)(ws + (2u << 20));
    float*  marr = (float*)(ws + (3u << 20));
    float*  rarr = (float*)(ws + (3u << 20) + (1u << 15));

    k1_proj<<<dim3(64, 3), 256, 0, stream>>>(x, Wq, bq, Wk, bk, Wv, bv, Qbf, Kbf, Vt);
    k2_stats<<<512, 256, 0, stream>>>(Qbf, Kbf, marr, rarr);
    k3_out<<<512, 256, 0, stream>>>(Qbf, Kbf, Vt, mask, marr, rarr, out);
}